// Round 5
// baseline (304.587 us; speedup 1.0000x reference)
//
#include <hip/hip_runtime.h>
#include <math.h>

#define NPARTS 64
#define CELL 28
#define CDIM 2048
#define BDIM 256
#define SPLIT 8
#define CH_PER_BLOCK (CDIM / SPLIT)     // 256 channels per block
#define DIS_BLOCKS (BDIM * SPLIT)       // 2048 blocks for dis phase

// ---- d_ws layout (float offsets) ----
#define WS_SAME   0                                     // 16384
#define WS_PART   (WS_SAME + BDIM * NPARTS)             // 2048*192 = 393216
#define WS_MBT    (WS_PART + DIS_BLOCKS * 3 * NPARTS)
#define WS_MMT    (WS_MBT + CDIM * NPARTS)
#define WS_MNT    (WS_MMT + CDIM * NPARTS)
#define WS_CELL   (WS_MNT + CDIM * NPARTS)              // int cells, 16384
#define WS_TICKET (WS_CELL + BDIM * NPARTS)             // 1 uint

#define PREP_BLOCKS 1600   // 1600*256 = 3*CDIM*NPARTS + BDIM*NPARTS exactly

// ---------------------------------------------------------------------------
// Front kernel: blocks [0,1600) prep (mean transpose + cell precompute +
// ticket reset); blocks [1600,1856) do distances_im + val for b = g-1600.
// ---------------------------------------------------------------------------
__global__ __launch_bounds__(256) void k_front(
    const float* __restrict__ mb, const float* __restrict__ mm,
    const float* __restrict__ mn, const int* __restrict__ cx,
    const int* __restrict__ cy,
    const float* __restrict__ emb,
    const float* __restrict__ meb, const float* __restrict__ mem_,
    const float* __restrict__ men,
    float* __restrict__ ws, float* __restrict__ out)
{
    const int g = blockIdx.x;
    const int t = threadIdx.x;

    if (g < PREP_BLOCKS) {
        if (g == 0 && t == 0) ((unsigned*)ws)[WS_TICKET] = 0u;   // reset ticket
        const int tid = g * 256 + t;
        const int NM = CDIM * NPARTS;               // 131072 = 2^17
        if (tid < 3 * NM) {
            const int kind = tid >> 17;
            const int idx  = tid & (NM - 1);
            const int p = idx >> 11;
            const int c = idx & (CDIM - 1);
            const float* src = (kind == 0) ? mb : (kind == 1) ? mm : mn;
            float* dst = ws + ((kind == 0) ? WS_MBT : (kind == 1) ? WS_MMT : WS_MNT);
            dst[((c >> 2) << 8) + (p << 2) + (c & 3)] = src[idx];
        } else {
            const int t2 = tid - 3 * NM;            // < BDIM*NPARTS
            const int b = t2 & (BDIM - 1);
            const int p = t2 >> 8;
            const int x = cx[t2] / CELL;
            const int y = cy[t2] / CELL;
            ((int*)ws)[WS_CELL + b * NPARTS + p] = x * 8 + y;
        }
        return;
    }

    // ---- distances_im + val ----
    const int b = g - PREP_BLOCKS;
    const float* e = emb + (size_t)b * CDIM;

    float sb = 0.f, sm = 0.f, sn = 0.f;
    for (int c = t; c < CDIM; c += 256) {
        float v = e[c];
        float d0 = v - meb[c];  sb += d0 * d0;
        float d1 = v - mem_[c]; sm += d1 * d1;
        float d2 = v - men[c];  sn += d2 * d2;
    }
    for (int off = 32; off; off >>= 1) {
        sb += __shfl_down(sb, off);
        sm += __shfl_down(sm, off);
        sn += __shfl_down(sn, off);
    }
    __shared__ float red[3][4];
    const int wave = t >> 6;
    if ((t & 63) == 0) { red[0][wave] = sb; red[1][wave] = sm; red[2][wave] = sn; }
    __syncthreads();
    if (t == 0) {
        float tb = red[0][0] + red[0][1] + red[0][2] + red[0][3];
        float tm = red[1][0] + red[1][1] + red[1][2] + red[1][3];
        float tn = red[2][0] + red[2][1] + red[2][2] + red[2][3];
        float db = sqrtf(tb), dm = sqrtf(tm), dn = sqrtf(tn);
        out[b * 3 + 0] = db;
        out[b * 3 + 1] = dm;
        out[b * 3 + 2] = dn;
        int idx = 0; float best = db;
        if (dm < best) { best = dm; idx = 1; }
        if (dn < best) { idx = 2; }
        out[3 * BDIM + b] = (float)idx;
    }
}

// ---------------------------------------------------------------------------
// Main kernel: R3's proven dis mapping (block g = b*8+s, one image, 256
// channels, 4 waves, lane = part; coalesced fm + ds_bpermute), then a
// last-block fused epilogue (combine + sqrt + same + loss) gated by a
// device-scope atomic ticket. Deterministic: fixed-order sums in the one
// designated tail block.
// ---------------------------------------------------------------------------
__global__ __launch_bounds__(256) void k_main(
    const float* __restrict__ fm,
    const int* __restrict__ labels,
    float* __restrict__ ws, float* __restrict__ out)
{
    const int g = blockIdx.x;              // = b*8 + s
    const int b = g >> 3, s = g & 7;
    const int t = threadIdx.x;
    const int lane = t & 63, w = t >> 6;

    const int cell  = ((const int*)ws)[WS_CELL + b * NPARTS + lane];
    const int baddr = cell << 2;           // byte address for bpermute

    const int c0 = s * CH_PER_BLOCK + w * 64;     // this wave's first channel
    const float* fmb = fm + (size_t)b * (CDIM * 64) + (size_t)c0 * 64;
    const float4* mbt = (const float4*)(ws + WS_MBT) + ((c0 >> 2) << 6) + lane;
    const float4* mmt = (const float4*)(ws + WS_MMT) + ((c0 >> 2) << 6) + lane;
    const float4* mnt = (const float4*)(ws + WS_MNT) + ((c0 >> 2) << 6) + lane;

    float a0 = 0.f, a1 = 0.f, a2 = 0.f;
    #pragma unroll 4
    for (int k = 0; k < 16; ++k) {          // 4 channels per iter
        const float* r = fmb + k * 256;
        float v0 = r[lane];
        float v1 = r[64 + lane];
        float v2 = r[128 + lane];
        float v3 = r[192 + lane];
        float4 m0 = mbt[k * 64];
        float4 m1 = mmt[k * 64];
        float4 m2 = mnt[k * 64];
        float u0 = __int_as_float(__builtin_amdgcn_ds_bpermute(baddr, __float_as_int(v0)));
        float u1 = __int_as_float(__builtin_amdgcn_ds_bpermute(baddr, __float_as_int(v1)));
        float u2 = __int_as_float(__builtin_amdgcn_ds_bpermute(baddr, __float_as_int(v2)));
        float u3 = __int_as_float(__builtin_amdgcn_ds_bpermute(baddr, __float_as_int(v3)));
        float d;
        d = u0 - m0.x; a0 += d * d;  d = u1 - m0.y; a0 += d * d;
        d = u2 - m0.z; a0 += d * d;  d = u3 - m0.w; a0 += d * d;
        d = u0 - m1.x; a1 += d * d;  d = u1 - m1.y; a1 += d * d;
        d = u2 - m1.z; a1 += d * d;  d = u3 - m1.w; a1 += d * d;
        d = u0 - m2.x; a2 += d * d;  d = u1 - m2.y; a2 += d * d;
        d = u2 - m2.z; a2 += d * d;  d = u3 - m2.w; a2 += d * d;
    }

    __shared__ float red[4][3][64];
    red[w][0][lane] = a0; red[w][1][lane] = a1; red[w][2][lane] = a2;
    __syncthreads();
    if (t < 64) {
        float s0 = red[0][0][t] + red[1][0][t] + red[2][0][t] + red[3][0][t];
        float s1 = red[0][1][t] + red[1][1][t] + red[2][1][t] + red[3][1][t];
        float s2 = red[0][2][t] + red[1][2][t] + red[2][2][t] + red[3][2][t];
        float* po = ws + WS_PART + (size_t)g * 192;
        po[t] = s0; po[64 + t] = s1; po[128 + t] = s2;
    }

    // ---- last-block fused epilogue ----
    __threadfence();                         // release: partials visible device-wide
    __shared__ unsigned ticket;
    if (t == 0) ticket = atomicAdd(&((unsigned*)ws)[WS_TICKET], 1u);
    __syncthreads();
    if (ticket != DIS_BLOCKS - 1) return;
    __threadfence();                         // acquire: see all partials

    const int N = BDIM * NPARTS;             // 16384
    double ssum = 0.0, s3sum = 0.0;

    // combine: sqrt(sum of 8 slice partials), fixed order (deterministic)
    for (int gid = t; gid < N; gid += 256) {
        const int bb = gid >> 6, p = gid & 63;
        const float* pp = ws + WS_PART + (size_t)(bb * SPLIT) * 192;
        float s0 = 0.f, s1 = 0.f, s2 = 0.f;
        #pragma unroll
        for (int sl = 0; sl < SPLIT; ++sl) {
            s0 += pp[sl * 192 + p];
            s1 += pp[sl * 192 + 64 + p];
            s2 += pp[sl * 192 + 128 + p];
        }
        float db = sqrtf(s0), dm = sqrtf(s1), dn = sqrtf(s2);
        const int lab = labels[bb];
        float same_v = (lab == 0) ? db : ((lab == 1) ? dm : dn);
        ws[WS_SAME + gid] = same_v;
        ssum  += (double)same_v;
        s3sum += (double)(db + dm + dn);
    }

    __shared__ double r1[256], r2[256];
    r1[t] = s3sum; r2[t] = ssum;
    __syncthreads();
    for (int off = 128; off; off >>= 1) {
        if (t < off) { r1[t] += r1[t + off]; r2[t] += r2[t + off]; }
        __syncthreads();
    }
    __shared__ float dmS;
    if (t == 0) dmS = (float)((r1[0] - r2[0]) / (double)(BDIM * 2 * NPARTS));
    __syncthreads();
    const float dmean = dmS;

    double sl = 0.0;
    for (int gid = t; gid < N; gid += 256) {
        float v = 1.0f + ws[WS_SAME + gid] - dmean;
        sl += (v > 0.f) ? (double)v : 0.0;
    }
    r1[t] = sl;
    __syncthreads();
    for (int off = 128; off; off >>= 1) {
        if (t < off) r1[t] += r1[t + off];
        __syncthreads();
    }
    if (t == 0) out[3 * BDIM + BDIM] = (float)(r1[0] / (double)N);
}

extern "C" void kernel_launch(void* const* d_in, const int* in_sizes, int n_in,
                              void* d_out, int out_size, void* d_ws, size_t ws_size,
                              hipStream_t stream)
{
    const int*   labels = (const int*)  d_in[0];
    const float* emb    = (const float*)d_in[1];
    const float* fm     = (const float*)d_in[2];
    const float* mb     = (const float*)d_in[3];
    const float* mm     = (const float*)d_in[4];
    const float* mn     = (const float*)d_in[5];
    const int*   cx     = (const int*)  d_in[6];
    const int*   cy     = (const int*)  d_in[7];
    const float* meb    = (const float*)d_in[8];
    const float* mem_   = (const float*)d_in[9];
    const float* men    = (const float*)d_in[10];

    float* out = (float*)d_out;
    float* ws  = (float*)d_ws;

    k_front<<<PREP_BLOCKS + BDIM, 256, 0, stream>>>(mb, mm, mn, cx, cy,
                                                    emb, meb, mem_, men, ws, out);
    k_main<<<DIS_BLOCKS, 256, 0, stream>>>(fm, labels, ws, out);
}

// Round 6
// 58.519 us; speedup vs baseline: 5.2049x; 5.2049x over previous
//
#include <hip/hip_runtime.h>
#include <math.h>

#define NPARTS 64
#define CELL 28
#define CDIM 2048
#define BDIM 256

// ---- d_ws layout (float offsets) ----
#define WS_SAME   0                                   // 16384 floats
#define WS_MBT    (WS_SAME + BDIM * NPARTS)           // 16384
#define WS_MMT    (WS_MBT + CDIM * NPARTS)            // +131072
#define WS_MNT    (WS_MMT + CDIM * NPARTS)
#define WS_CELL   (WS_MNT + CDIM * NPARTS)            // int cells, 16384
#define WS_IMG    (WS_CELL + BDIM * NPARTS)           // 256*2 doubles (even offset)

#define PREP_BLOCKS 1600   // 1600*256 = 3*CDIM*NPARTS + BDIM*NPARTS exactly

// ---------------------------------------------------------------------------
// Front kernel: blocks [0,1600) prep (mean transpose [p][c]->[c/4][p][4] +
// cell precompute); blocks [1600,1856) distances_im + val for b = g-1600.
// ---------------------------------------------------------------------------
__global__ __launch_bounds__(256) void k_front(
    const float* __restrict__ mb, const float* __restrict__ mm,
    const float* __restrict__ mn, const int* __restrict__ cx,
    const int* __restrict__ cy,
    const float* __restrict__ emb,
    const float* __restrict__ meb, const float* __restrict__ mem_,
    const float* __restrict__ men,
    float* __restrict__ ws, float* __restrict__ out)
{
    const int g = blockIdx.x;
    const int t = threadIdx.x;

    if (g < PREP_BLOCKS) {
        const int tid = g * 256 + t;
        const int NM = CDIM * NPARTS;               // 131072 = 2^17
        if (tid < 3 * NM) {
            const int kind = tid >> 17;
            const int idx  = tid & (NM - 1);
            const int p = idx >> 11;
            const int c = idx & (CDIM - 1);
            const float* src = (kind == 0) ? mb : (kind == 1) ? mm : mn;
            float* dst = ws + ((kind == 0) ? WS_MBT : (kind == 1) ? WS_MMT : WS_MNT);
            dst[((c >> 2) << 8) + (p << 2) + (c & 3)] = src[idx];
        } else {
            const int t2 = tid - 3 * NM;            // < BDIM*NPARTS
            const int b = t2 & (BDIM - 1);
            const int p = t2 >> 8;
            const int x = cx[t2] / CELL;
            const int y = cy[t2] / CELL;
            ((int*)ws)[WS_CELL + b * NPARTS + p] = x * 8 + y;
        }
        return;
    }

    // ---- distances_im + val ----
    const int b = g - PREP_BLOCKS;
    const float* e = emb + (size_t)b * CDIM;

    float sb = 0.f, sm = 0.f, sn = 0.f;
    for (int c = t; c < CDIM; c += 256) {
        float v = e[c];
        float d0 = v - meb[c];  sb += d0 * d0;
        float d1 = v - mem_[c]; sm += d1 * d1;
        float d2 = v - men[c];  sn += d2 * d2;
    }
    for (int off = 32; off; off >>= 1) {
        sb += __shfl_down(sb, off);
        sm += __shfl_down(sm, off);
        sn += __shfl_down(sn, off);
    }
    __shared__ float red[3][4];
    const int wave = t >> 6;
    if ((t & 63) == 0) { red[0][wave] = sb; red[1][wave] = sm; red[2][wave] = sn; }
    __syncthreads();
    if (t == 0) {
        float tb = red[0][0] + red[0][1] + red[0][2] + red[0][3];
        float tm = red[1][0] + red[1][1] + red[1][2] + red[1][3];
        float tn = red[2][0] + red[2][1] + red[2][2] + red[2][3];
        float db = sqrtf(tb), dm = sqrtf(tm), dn = sqrtf(tn);
        out[b * 3 + 0] = db;
        out[b * 3 + 1] = dm;
        out[b * 3 + 2] = dn;
        int idx = 0; float best = db;
        if (dm < best) { best = dm; idx = 1; }
        if (dn < best) { idx = 2; }
        out[3 * BDIM + b] = (float)idx;
    }
}

// ---------------------------------------------------------------------------
// Dis kernel: one block per image (256 blocks x 1024 threads, 16 waves).
// Wave w covers channels [w*128, w*128+128); lane = part p. Coalesced
// nontemporal fm loads (each line consumed exactly once on the device) +
// ds_bpermute to route cell values to parts. In-block LDS reduction over
// the 16 waves, then sqrt/same/sum3 + per-image double partial sums.
// No cross-block communication -> no fences, no combine dispatch.
// ---------------------------------------------------------------------------
__global__ __launch_bounds__(1024) void k_dis3(
    const float* __restrict__ fm,
    const int* __restrict__ labels,
    float* __restrict__ ws, double* __restrict__ dimg)
{
    const int b = blockIdx.x;
    const int t = threadIdx.x;
    const int lane = t & 63, w = t >> 6;

    const int cell  = ((const int*)ws)[WS_CELL + b * NPARTS + lane];
    const int baddr = cell << 2;

    const int c0 = w * 128;
    const float* fmb = fm + (size_t)b * (CDIM * 64) + (size_t)c0 * 64;
    const float4* mbt = (const float4*)(ws + WS_MBT) + ((c0 >> 2) << 6) + lane;
    const float4* mmt = (const float4*)(ws + WS_MMT) + ((c0 >> 2) << 6) + lane;
    const float4* mnt = (const float4*)(ws + WS_MNT) + ((c0 >> 2) << 6) + lane;

    float a0 = 0.f, a1 = 0.f, a2 = 0.f;
    #pragma unroll 4
    for (int k = 0; k < 32; ++k) {          // 4 channels per iter
        const float* r = fmb + k * 256;
        float v0 = __builtin_nontemporal_load(r + lane);
        float v1 = __builtin_nontemporal_load(r + 64 + lane);
        float v2 = __builtin_nontemporal_load(r + 128 + lane);
        float v3 = __builtin_nontemporal_load(r + 192 + lane);
        float4 m0 = mbt[k * 64];
        float4 m1 = mmt[k * 64];
        float4 m2 = mnt[k * 64];
        float u0 = __int_as_float(__builtin_amdgcn_ds_bpermute(baddr, __float_as_int(v0)));
        float u1 = __int_as_float(__builtin_amdgcn_ds_bpermute(baddr, __float_as_int(v1)));
        float u2 = __int_as_float(__builtin_amdgcn_ds_bpermute(baddr, __float_as_int(v2)));
        float u3 = __int_as_float(__builtin_amdgcn_ds_bpermute(baddr, __float_as_int(v3)));
        float d;
        d = u0 - m0.x; a0 += d * d;  d = u1 - m0.y; a0 += d * d;
        d = u2 - m0.z; a0 += d * d;  d = u3 - m0.w; a0 += d * d;
        d = u0 - m1.x; a1 += d * d;  d = u1 - m1.y; a1 += d * d;
        d = u2 - m1.z; a1 += d * d;  d = u3 - m1.w; a1 += d * d;
        d = u0 - m2.x; a2 += d * d;  d = u1 - m2.y; a2 += d * d;
        d = u2 - m2.z; a2 += d * d;  d = u3 - m2.w; a2 += d * d;
    }

    __shared__ float red[16][3][64];
    __shared__ float sm2[3][64];
    red[w][0][lane] = a0; red[w][1][lane] = a1; red[w][2][lane] = a2;
    __syncthreads();

    if (t < 192) {
        const int j = t >> 6, p = t & 63;
        float s = 0.f;
        #pragma unroll
        for (int ww = 0; ww < 16; ++ww) s += red[ww][j][p];
        sm2[j][p] = s;
    }
    __syncthreads();

    if (t < 64) {                       // wave 0 only
        float db = sqrtf(sm2[0][t]);
        float dm = sqrtf(sm2[1][t]);
        float dn = sqrtf(sm2[2][t]);
        const int lab = labels[b];
        float same_v = (lab == 0) ? db : ((lab == 1) ? dm : dn);
        ws[WS_SAME + b * NPARTS + t] = same_v;
        double ds = (double)same_v;
        double d3 = (double)(db + dm + dn);
        for (int off = 32; off; off >>= 1) {
            ds += __shfl_down(ds, off);
            d3 += __shfl_down(d3, off);
        }
        if (t == 0) { dimg[2 * b] = ds; dimg[2 * b + 1] = d3; }
    }
}

// ---------------------------------------------------------------------------
// Deterministic final loss (single block, 512 threads)
// ---------------------------------------------------------------------------
__global__ __launch_bounds__(512) void k_loss(
    const float* __restrict__ ws, const double* __restrict__ dimg,
    float* __restrict__ out)
{
    const int t = threadIdx.x;
    const int N = BDIM * NPARTS;
    const float* same = ws + WS_SAME;

    double ss = 0.0, s3 = 0.0;
    if (t < BDIM) { ss = dimg[2 * t]; s3 = dimg[2 * t + 1]; }

    __shared__ double r1[512], r2[512];
    r1[t] = s3; r2[t] = ss;
    __syncthreads();
    for (int off = 256; off; off >>= 1) {
        if (t < off) { r1[t] += r1[t + off]; r2[t] += r2[t + off]; }
        __syncthreads();
    }
    __shared__ float dmS;
    if (t == 0) dmS = (float)((r1[0] - r2[0]) / (double)(BDIM * 2 * NPARTS));
    __syncthreads();
    const float dmean = dmS;

    double sl = 0.0;
    for (int i = t; i < N; i += 512) {
        float v = 1.0f + same[i] - dmean;
        sl += (v > 0.f) ? (double)v : 0.0;
    }
    r1[t] = sl;
    __syncthreads();
    for (int off = 256; off; off >>= 1) {
        if (t < off) r1[t] += r1[t + off];
        __syncthreads();
    }
    if (t == 0) out[3 * BDIM + BDIM] = (float)(r1[0] / (double)N);
}

extern "C" void kernel_launch(void* const* d_in, const int* in_sizes, int n_in,
                              void* d_out, int out_size, void* d_ws, size_t ws_size,
                              hipStream_t stream)
{
    const int*   labels = (const int*)  d_in[0];
    const float* emb    = (const float*)d_in[1];
    const float* fm     = (const float*)d_in[2];
    const float* mb     = (const float*)d_in[3];
    const float* mm     = (const float*)d_in[4];
    const float* mn     = (const float*)d_in[5];
    const int*   cx     = (const int*)  d_in[6];
    const int*   cy     = (const int*)  d_in[7];
    const float* meb    = (const float*)d_in[8];
    const float* mem_   = (const float*)d_in[9];
    const float* men    = (const float*)d_in[10];

    float*  out  = (float*)d_out;
    float*  ws   = (float*)d_ws;
    double* dimg = (double*)(ws + WS_IMG);

    k_front<<<PREP_BLOCKS + BDIM, 256, 0, stream>>>(mb, mm, mn, cx, cy,
                                                    emb, meb, mem_, men, ws, out);
    k_dis3<<<BDIM, 1024, 0, stream>>>(fm, labels, ws, dimg);
    k_loss<<<1, 512, 0, stream>>>(ws, dimg, out);
}

// Round 7
// 52.936 us; speedup vs baseline: 5.7538x; 1.1055x over previous
//
#include <hip/hip_runtime.h>
#include <math.h>

#define NPARTS 64
#define CELL 28
#define CDIM 2048
#define BDIM 256
#define SPLIT 8
#define CH_PER_BLOCK (CDIM / SPLIT)     // 256 channels per slice-block
#define DIS_BLOCKS (BDIM * SPLIT)       // 2048

// ---- d_ws layout (float offsets) ----
#define WS_SAME   0                                     // 16384
#define WS_PART   (WS_SAME + BDIM * NPARTS)             // 2048*192
#define WS_MBT    (WS_PART + DIS_BLOCKS * 3 * NPARTS)
#define WS_MMT    (WS_MBT + CDIM * NPARTS)
#define WS_MNT    (WS_MMT + CDIM * NPARTS)
#define WS_CELL   (WS_MNT + CDIM * NPARTS)              // int cells, 16384
#define WS_DIMG   (WS_CELL + BDIM * NPARTS)             // 256*2 doubles (8B-aligned)
#define WS_TICK   (WS_DIMG + 2 * BDIM * 2)              // 256 image tickets + 1 global

#define PREP_BLOCKS 1600   // 1600*256 = 3*CDIM*NPARTS + BDIM*NPARTS exactly

// ---------------------------------------------------------------------------
// Front kernel: blocks [0,1600) prep (mean transpose [p][c]->[c/4][p][4],
// cell precompute, ticket reset); blocks [1600,1856) distances_im + val.
// ---------------------------------------------------------------------------
__global__ __launch_bounds__(256) void k_front(
    const float* __restrict__ mb, const float* __restrict__ mm,
    const float* __restrict__ mn, const int* __restrict__ cx,
    const int* __restrict__ cy,
    const float* __restrict__ emb,
    const float* __restrict__ meb, const float* __restrict__ mem_,
    const float* __restrict__ men,
    float* __restrict__ ws, float* __restrict__ out)
{
    const int g = blockIdx.x;
    const int t = threadIdx.x;

    if (g < PREP_BLOCKS) {
        if (g == 0) {                       // reset tickets (fresh every launch)
            unsigned* tick = (unsigned*)(ws + WS_TICK);
            if (t < BDIM) tick[t] = 0u;
            if (t == 0) tick[BDIM] = 0u;
        }
        const int tid = g * 256 + t;
        const int NM = CDIM * NPARTS;               // 131072 = 2^17
        if (tid < 3 * NM) {
            const int kind = tid >> 17;
            const int idx  = tid & (NM - 1);
            const int p = idx >> 11;
            const int c = idx & (CDIM - 1);
            const float* src = (kind == 0) ? mb : (kind == 1) ? mm : mn;
            float* dst = ws + ((kind == 0) ? WS_MBT : (kind == 1) ? WS_MMT : WS_MNT);
            dst[((c >> 2) << 8) + (p << 2) + (c & 3)] = src[idx];
        } else {
            const int t2 = tid - 3 * NM;            // < BDIM*NPARTS
            const int b = t2 & (BDIM - 1);
            const int p = t2 >> 8;
            const int x = cx[t2] / CELL;
            const int y = cy[t2] / CELL;
            ((int*)ws)[WS_CELL + b * NPARTS + p] = x * 8 + y;
        }
        return;
    }

    // ---- distances_im + val ----
    const int b = g - PREP_BLOCKS;
    const float* e = emb + (size_t)b * CDIM;

    float sb = 0.f, sm = 0.f, sn = 0.f;
    for (int c = t; c < CDIM; c += 256) {
        float v = e[c];
        float d0 = v - meb[c];  sb += d0 * d0;
        float d1 = v - mem_[c]; sm += d1 * d1;
        float d2 = v - men[c];  sn += d2 * d2;
    }
    for (int off = 32; off; off >>= 1) {
        sb += __shfl_down(sb, off);
        sm += __shfl_down(sm, off);
        sn += __shfl_down(sn, off);
    }
    __shared__ float red[3][4];
    const int wave = t >> 6;
    if ((t & 63) == 0) { red[0][wave] = sb; red[1][wave] = sm; red[2][wave] = sn; }
    __syncthreads();
    if (t == 0) {
        float tb = red[0][0] + red[0][1] + red[0][2] + red[0][3];
        float tm = red[1][0] + red[1][1] + red[1][2] + red[1][3];
        float tn = red[2][0] + red[2][1] + red[2][2] + red[2][3];
        float db = sqrtf(tb), dm = sqrtf(tm), dn = sqrtf(tn);
        out[b * 3 + 0] = db;
        out[b * 3 + 1] = dm;
        out[b * 3 + 2] = dn;
        int idx = 0; float best = db;
        if (dm < best) { best = dm; idx = 1; }
        if (dn < best) { idx = 2; }
        out[3 * BDIM + b] = (float)idx;
    }
}

// ---------------------------------------------------------------------------
// Dis kernel + fused epilogues.
// Block g: slice s = g>>8, image b = g&255  =>  g % 8 == b % 8: all 8 slice
// blocks of an image land on ONE XCD (round-robin dispatch), so their
// partials are coherent in that XCD's L2 -- no fences needed. 8th arriver
// (relaxed atomic ticket after vmcnt(0)) reduces the image (L1-bypass
// loads), publishes same/dimg via atomicExch (coherence point). 256th
// image-winner computes dmean + hinge loss.
// ---------------------------------------------------------------------------
__global__ __launch_bounds__(256, 8) void k_dis(
    const float* __restrict__ fm,
    const int* __restrict__ labels,
    float* __restrict__ ws, float* __restrict__ out)
{
    const int g = blockIdx.x;
    const int s = g >> 8, b = g & (BDIM - 1);
    const int t = threadIdx.x;
    const int lane = t & 63, w = t >> 6;

    const int cell  = ((const int*)ws)[WS_CELL + b * NPARTS + lane];
    const int baddr = cell << 2;

    const int c0 = s * CH_PER_BLOCK + w * 64;
    const float* fmb = fm + (size_t)b * (CDIM * 64) + (size_t)c0 * 64;
    const float4* mbt = (const float4*)(ws + WS_MBT) + ((c0 >> 2) << 6) + lane;
    const float4* mmt = (const float4*)(ws + WS_MMT) + ((c0 >> 2) << 6) + lane;
    const float4* mnt = (const float4*)(ws + WS_MNT) + ((c0 >> 2) << 6) + lane;

    float a0 = 0.f, a1 = 0.f, a2 = 0.f;
    #pragma unroll 4
    for (int k = 0; k < 16; ++k) {          // 4 channels per iter
        const float* r = fmb + k * 256;
        float v0 = r[lane];
        float v1 = r[64 + lane];
        float v2 = r[128 + lane];
        float v3 = r[192 + lane];
        float4 m0 = mbt[k * 64];
        float4 m1 = mmt[k * 64];
        float4 m2 = mnt[k * 64];
        float u0 = __int_as_float(__builtin_amdgcn_ds_bpermute(baddr, __float_as_int(v0)));
        float u1 = __int_as_float(__builtin_amdgcn_ds_bpermute(baddr, __float_as_int(v1)));
        float u2 = __int_as_float(__builtin_amdgcn_ds_bpermute(baddr, __float_as_int(v2)));
        float u3 = __int_as_float(__builtin_amdgcn_ds_bpermute(baddr, __float_as_int(v3)));
        float d;
        d = u0 - m0.x; a0 += d * d;  d = u1 - m0.y; a0 += d * d;
        d = u2 - m0.z; a0 += d * d;  d = u3 - m0.w; a0 += d * d;
        d = u0 - m1.x; a1 += d * d;  d = u1 - m1.y; a1 += d * d;
        d = u2 - m1.z; a1 += d * d;  d = u3 - m1.w; a1 += d * d;
        d = u0 - m2.x; a2 += d * d;  d = u1 - m2.y; a2 += d * d;
        d = u2 - m2.z; a2 += d * d;  d = u3 - m2.w; a2 += d * d;
    }

    __shared__ float red[4][3][64];
    red[w][0][lane] = a0; red[w][1][lane] = a1; red[w][2][lane] = a2;
    __syncthreads();
    if (t < 64) {
        float s0 = red[0][0][t] + red[1][0][t] + red[2][0][t] + red[3][0][t];
        float s1 = red[0][1][t] + red[1][1][t] + red[2][1][t] + red[3][1][t];
        float s2 = red[0][2][t] + red[1][2][t] + red[2][2][t] + red[3][2][t];
        float* po = ws + WS_PART + (size_t)(b * SPLIT + s) * 192;
        po[t] = s0; po[64 + t] = s1; po[128 + t] = s2;
    }

    // ---- per-image ticket (no fence; partials stay in this XCD's L2) ----
    asm volatile("s_waitcnt vmcnt(0)" ::: "memory");   // partial stores in L2
    __shared__ unsigned flag;
    unsigned* tick = (unsigned*)(ws + WS_TICK);
    if (t == 0) flag = atomicAdd(&tick[b], 1u);
    __syncthreads();
    if (flag != SPLIT - 1) return;

    // ---- image epilogue (8th arriver; same XCD as all 8 writers) ----
    __shared__ float sm2[3][64];
    const float* pp = ws + WS_PART + (size_t)(b * SPLIT) * 192;
    if (t < 192) {
        const int j = t >> 6, p = t & 63;
        float acc = 0.f;
        #pragma unroll
        for (int sl = 0; sl < SPLIT; ++sl)
            acc += __hip_atomic_load(pp + sl * 192 + j * 64 + p,
                                     __ATOMIC_RELAXED, __HIP_MEMORY_SCOPE_AGENT);
        sm2[j][p] = acc;
    }
    __syncthreads();

    double* dimg = (double*)(ws + WS_DIMG);
    if (t < 64) {
        float db = sqrtf(sm2[0][t]);
        float dm = sqrtf(sm2[1][t]);
        float dn = sqrtf(sm2[2][t]);
        const int lab = labels[b];
        float same_v = (lab == 0) ? db : ((lab == 1) ? dm : dn);
        atomicExch(&ws[WS_SAME + b * NPARTS + t], same_v);   // coherence point
        double ds = (double)same_v;
        double d3 = (double)(db + dm + dn);
        for (int off = 32; off; off >>= 1) {
            ds += __shfl_down(ds, off);
            d3 += __shfl_down(d3, off);
        }
        if (t == 0) {
            atomicExch((unsigned long long*)&dimg[2 * b],     (unsigned long long)__double_as_longlong(ds));
            atomicExch((unsigned long long*)&dimg[2 * b + 1], (unsigned long long)__double_as_longlong(d3));
        }
    }

    // ---- global ticket for the loss ----
    asm volatile("s_waitcnt vmcnt(0)" ::: "memory");
    if (t == 0) flag = atomicAdd(&tick[BDIM], 1u);
    __syncthreads();
    if (flag != BDIM - 1) return;

    // ---- final loss (256th image-winner; reads coherence-point values) ----
    double ss = 0.0, s3 = 0.0;
    if (t < BDIM) {
        ss = __hip_atomic_load(&dimg[2 * t],     __ATOMIC_RELAXED, __HIP_MEMORY_SCOPE_AGENT);
        s3 = __hip_atomic_load(&dimg[2 * t + 1], __ATOMIC_RELAXED, __HIP_MEMORY_SCOPE_AGENT);
    }
    __shared__ double r1[256], r2[256];
    r1[t] = s3; r2[t] = ss;
    __syncthreads();
    for (int off = 128; off; off >>= 1) {
        if (t < off) { r1[t] += r1[t + off]; r2[t] += r2[t + off]; }
        __syncthreads();
    }
    __shared__ float dmS;
    if (t == 0) dmS = (float)((r1[0] - r2[0]) / (double)(BDIM * 2 * NPARTS));
    __syncthreads();
    const float dmean = dmS;

    const int N = BDIM * NPARTS;
    double sl = 0.0;
    #pragma unroll 4
    for (int i = t; i < N; i += 256) {
        float sv = __hip_atomic_load(&ws[WS_SAME + i],
                                     __ATOMIC_RELAXED, __HIP_MEMORY_SCOPE_AGENT);
        float v = 1.0f + sv - dmean;
        sl += (v > 0.f) ? (double)v : 0.0;
    }
    r1[t] = sl;
    __syncthreads();
    for (int off = 128; off; off >>= 1) {
        if (t < off) r1[t] += r1[t + off];
        __syncthreads();
    }
    if (t == 0) out[3 * BDIM + BDIM] = (float)(r1[0] / (double)N);
}

extern "C" void kernel_launch(void* const* d_in, const int* in_sizes, int n_in,
                              void* d_out, int out_size, void* d_ws, size_t ws_size,
                              hipStream_t stream)
{
    const int*   labels = (const int*)  d_in[0];
    const float* emb    = (const float*)d_in[1];
    const float* fm     = (const float*)d_in[2];
    const float* mb     = (const float*)d_in[3];
    const float* mm     = (const float*)d_in[4];
    const float* mn     = (const float*)d_in[5];
    const int*   cx     = (const int*)  d_in[6];
    const int*   cy     = (const int*)  d_in[7];
    const float* meb    = (const float*)d_in[8];
    const float* mem_   = (const float*)d_in[9];
    const float* men    = (const float*)d_in[10];

    float* out = (float*)d_out;
    float* ws  = (float*)d_ws;

    k_front<<<PREP_BLOCKS + BDIM, 256, 0, stream>>>(mb, mm, mn, cx, cy,
                                                    emb, meb, mem_, men, ws, out);
    k_dis<<<DIS_BLOCKS, 256, 0, stream>>>(fm, labels, ws, out);
}

// Round 9
// 47.200 us; speedup vs baseline: 6.4531x; 1.1215x over previous
//
#include <hip/hip_runtime.h>
#include <math.h>

#define NPARTS 64
#define CELL 28
#define CDIM 2048
#define BDIM 256
#define SPLIT 8
#define CH_PER_BLOCK (CDIM / SPLIT)     // 256 channels per block
#define DIS_BLOCKS (BDIM * SPLIT)       // 2048 blocks for dis phase

// ---- d_ws layout (float offsets) ----
#define WS_SAME   0
#define WS_SUM3   (WS_SAME + BDIM * NPARTS)             // 16384
#define WS_PART   (WS_SUM3 + BDIM * NPARTS)             // 32768, 2048*192
#define WS_MBT    (WS_PART + DIS_BLOCKS * 3 * NPARTS)   // f16 tables (negated)
#define WS_MMT    (WS_MBT + CDIM * NPARTS / 2)          // each = 65536 floats
#define WS_MNT    (WS_MMT + CDIM * NPARTS / 2)
#define WS_CELL   (WS_MNT + CDIM * NPARTS / 2)          // int cells, 16384

#define PREP_BLOCKS 1600   // 1600*256 = 3*CDIM*NPARTS + BDIM*NPARTS exactly

typedef _Float16 h2_t __attribute__((ext_vector_type(2)));

static __device__ __forceinline__ h2_t bperm_h2(int baddr, h2_t v) {
    int r = __builtin_amdgcn_ds_bpermute(baddr, __builtin_bit_cast(int, v));
    return __builtin_bit_cast(h2_t, r);
}

static __device__ __forceinline__ h2_t pack_h2(float a, float b) {
    return __builtin_bit_cast(h2_t, __builtin_amdgcn_cvt_pkrtz(a, b));
}

// ---------------------------------------------------------------------------
// Front kernel: blocks [0,1600) prep; blocks [1600,1856) distances_im + val.
// Prep stores means transposed, NEGATED, as f16:
//   u16_table[(c>>2)*256 + (p<<2) + (c&3)] = f16(-m[p][c])
// so k_dis2 loads one dwordx2 per (4 channels, part, kind) and subtracts
// via v_pk_add_f16.
// ---------------------------------------------------------------------------
__global__ __launch_bounds__(256) void k_front(
    const float* __restrict__ mb, const float* __restrict__ mm,
    const float* __restrict__ mn, const int* __restrict__ cx,
    const int* __restrict__ cy,
    const float* __restrict__ emb,
    const float* __restrict__ meb, const float* __restrict__ mem_,
    const float* __restrict__ men,
    float* __restrict__ ws, float* __restrict__ out)
{
    const int g = blockIdx.x;
    const int t = threadIdx.x;

    if (g < PREP_BLOCKS) {
        const int tid = g * 256 + t;
        const int NM = CDIM * NPARTS;               // 131072 = 2^17
        if (tid < 3 * NM) {
            const int kind = tid >> 17;
            const int idx  = tid & (NM - 1);
            const int p = idx >> 11;
            const int c = idx & (CDIM - 1);
            const float* src = (kind == 0) ? mb : (kind == 1) ? mm : mn;
            _Float16* dst = (_Float16*)(ws + ((kind == 0) ? WS_MBT :
                                              (kind == 1) ? WS_MMT : WS_MNT));
            dst[((c >> 2) << 8) + (p << 2) + (c & 3)] = (_Float16)(-src[idx]);
        } else {
            const int t2 = tid - 3 * NM;            // < BDIM*NPARTS
            const int b = t2 & (BDIM - 1);
            const int p = t2 >> 8;
            const int x = cx[t2] / CELL;
            const int y = cy[t2] / CELL;
            ((int*)ws)[WS_CELL + b * NPARTS + p] = x * 8 + y;
        }
        return;
    }

    // ---- distances_im + val (exact fp32 path) ----
    const int b = g - PREP_BLOCKS;
    const float* e = emb + (size_t)b * CDIM;

    float sb = 0.f, sm = 0.f, sn = 0.f;
    for (int c = t; c < CDIM; c += 256) {
        float v = e[c];
        float d0 = v - meb[c];  sb += d0 * d0;
        float d1 = v - mem_[c]; sm += d1 * d1;
        float d2 = v - men[c];  sn += d2 * d2;
    }
    for (int off = 32; off; off >>= 1) {
        sb += __shfl_down(sb, off);
        sm += __shfl_down(sm, off);
        sn += __shfl_down(sn, off);
    }
    __shared__ float red[3][4];
    const int wave = t >> 6;
    if ((t & 63) == 0) { red[0][wave] = sb; red[1][wave] = sm; red[2][wave] = sn; }
    __syncthreads();
    if (t == 0) {
        float tb = red[0][0] + red[0][1] + red[0][2] + red[0][3];
        float tm = red[1][0] + red[1][1] + red[1][2] + red[1][3];
        float tn = red[2][0] + red[2][1] + red[2][2] + red[2][3];
        float db = sqrtf(tb), dm = sqrtf(tm), dn = sqrtf(tn);
        out[b * 3 + 0] = db;
        out[b * 3 + 1] = dm;
        out[b * 3 + 2] = dn;
        int idx = 0; float best = db;
        if (dm < best) { best = dm; idx = 1; }
        if (dn < best) { idx = 2; }
        out[3 * BDIM + b] = (float)idx;
    }
}

// ---------------------------------------------------------------------------
// Dis kernel (R3 mapping, f16-packed math):
// block g = b*8+s, 4 waves, lane = part. Per 4 channels: 4 coalesced fm
// loads -> cvt_pkrtz pack (2 ch/dword) -> 2 bpermute (halved LDS traffic)
// -> v_pk_add_f16 with pre-negated f16 means -> v_pk_fma_f16 square-accum.
// f16 error only reaches `loss` (distances_im/val stay fp32); est. ~0.01.
// ---------------------------------------------------------------------------
__global__ __launch_bounds__(256) void k_dis2(
    const float* __restrict__ fm,
    float* __restrict__ ws)
{
    const int g = blockIdx.x;              // = b*8 + s
    const int b = g >> 3, s = g & 7;
    const int t = threadIdx.x;
    const int lane = t & 63, w = t >> 6;

    const int cell  = ((const int*)ws)[WS_CELL + b * NPARTS + lane];
    const int baddr = cell << 2;           // byte address for bpermute

    const int c0 = s * CH_PER_BLOCK + w * 64;     // this wave's first channel
    const float* fmb = fm + (size_t)b * (CDIM * 64) + (size_t)c0 * 64;
    const uint2* mbt = (const uint2*)(ws + WS_MBT) + ((c0 >> 2) << 6) + lane;
    const uint2* mmt = (const uint2*)(ws + WS_MMT) + ((c0 >> 2) << 6) + lane;
    const uint2* mnt = (const uint2*)(ws + WS_MNT) + ((c0 >> 2) << 6) + lane;

    h2_t A00 = {0, 0}, A01 = {0, 0};   // mean b, pair slots (c0c1 / c2c3)
    h2_t A10 = {0, 0}, A11 = {0, 0};   // mean m
    h2_t A20 = {0, 0}, A21 = {0, 0};   // mean n

    #pragma unroll 4
    for (int k = 0; k < 16; ++k) {          // 4 channels per iter
        const float* r = fmb + k * 256;
        float v0 = r[lane];
        float v1 = r[64 + lane];
        float v2 = r[128 + lane];
        float v3 = r[192 + lane];
        uint2 nmb = mbt[k * 64];
        uint2 nmm = mmt[k * 64];
        uint2 nmn = mnt[k * 64];

        h2_t p01 = pack_h2(v0, v1);
        h2_t p23 = pack_h2(v2, v3);
        h2_t u01 = bperm_h2(baddr, p01);
        h2_t u23 = bperm_h2(baddr, p23);

        h2_t d;
        d = u01 + __builtin_bit_cast(h2_t, nmb.x); A00 += d * d;
        d = u23 + __builtin_bit_cast(h2_t, nmb.y); A01 += d * d;
        d = u01 + __builtin_bit_cast(h2_t, nmm.x); A10 += d * d;
        d = u23 + __builtin_bit_cast(h2_t, nmm.y); A11 += d * d;
        d = u01 + __builtin_bit_cast(h2_t, nmn.x); A20 += d * d;
        d = u23 + __builtin_bit_cast(h2_t, nmn.y); A21 += d * d;
    }

    float a0 = (float)A00.x + (float)A00.y + (float)A01.x + (float)A01.y;
    float a1 = (float)A10.x + (float)A10.y + (float)A11.x + (float)A11.y;
    float a2 = (float)A20.x + (float)A20.y + (float)A21.x + (float)A21.y;

    __shared__ float red[4][3][64];
    red[w][0][lane] = a0; red[w][1][lane] = a1; red[w][2][lane] = a2;
    __syncthreads();
    if (t < 64) {
        float s0 = red[0][0][t] + red[1][0][t] + red[2][0][t] + red[3][0][t];
        float s1 = red[0][1][t] + red[1][1][t] + red[2][1][t] + red[3][1][t];
        float s2 = red[0][2][t] + red[1][2][t] + red[2][2][t] + red[3][2][t];
        float* po = ws + WS_PART + (size_t)g * 192;
        po[t] = s0; po[64 + t] = s1; po[128 + t] = s2;
    }
}

// ---------------------------------------------------------------------------
// Combine 8 channel-splits -> sqrt -> same/sum3
// ---------------------------------------------------------------------------
__global__ __launch_bounds__(256) void k_combine(
    const int* __restrict__ labels, float* __restrict__ ws)
{
    const int gid = blockIdx.x * 256 + threadIdx.x;   // 16384
    const int b = gid >> 6, p = gid & 63;
    const float* pp = ws + WS_PART + (size_t)(b * 8) * 192;
    float s0 = 0.f, s1 = 0.f, s2 = 0.f;
    #pragma unroll
    for (int s = 0; s < 8; ++s) {
        s0 += pp[s * 192 + p];
        s1 += pp[s * 192 + 64 + p];
        s2 += pp[s * 192 + 128 + p];
    }
    float db = sqrtf(s0), dm = sqrtf(s1), dn = sqrtf(s2);
    const int lab = labels[b];
    ws[WS_SAME + gid] = (lab == 0) ? db : ((lab == 1) ? dm : dn);
    ws[WS_SUM3 + gid] = db + dm + dn;
}

// ---------------------------------------------------------------------------
// Deterministic final loss (single block, 512 threads)
// ---------------------------------------------------------------------------
__global__ __launch_bounds__(512) void k_loss(
    const float* __restrict__ ws, float* __restrict__ out)
{
    const int t = threadIdx.x;
    const int N = BDIM * NPARTS;
    const float* same = ws + WS_SAME;
    const float* sum3 = ws + WS_SUM3;

    double s3 = 0.0, ss = 0.0;
    for (int i = t; i < N; i += 512) { s3 += (double)sum3[i]; ss += (double)same[i]; }

    __shared__ double r1[512], r2[512];
    r1[t] = s3; r2[t] = ss;
    __syncthreads();
    for (int off = 256; off; off >>= 1) {
        if (t < off) { r1[t] += r1[t + off]; r2[t] += r2[t + off]; }
        __syncthreads();
    }
    __shared__ float dmS;
    if (t == 0) dmS = (float)((r1[0] - r2[0]) / (double)(BDIM * 2 * NPARTS));
    __syncthreads();
    const float dmean = dmS;

    double sl = 0.0;
    for (int i = t; i < N; i += 512) {
        float v = 1.0f + same[i] - dmean;
        sl += (v > 0.f) ? (double)v : 0.0;
    }
    r1[t] = sl;
    __syncthreads();
    for (int off = 256; off; off >>= 1) {
        if (t < off) r1[t] += r1[t + off];
        __syncthreads();
    }
    if (t == 0) out[3 * BDIM + BDIM] = (float)(r1[0] / (double)N);
}

extern "C" void kernel_launch(void* const* d_in, const int* in_sizes, int n_in,
                              void* d_out, int out_size, void* d_ws, size_t ws_size,
                              hipStream_t stream)
{
    const int*   labels = (const int*)  d_in[0];
    const float* emb    = (const float*)d_in[1];
    const float* fm     = (const float*)d_in[2];
    const float* mb     = (const float*)d_in[3];
    const float* mm     = (const float*)d_in[4];
    const float* mn     = (const float*)d_in[5];
    const int*   cx     = (const int*)  d_in[6];
    const int*   cy     = (const int*)  d_in[7];
    const float* meb    = (const float*)d_in[8];
    const float* mem_   = (const float*)d_in[9];
    const float* men    = (const float*)d_in[10];

    float* out = (float*)d_out;
    float* ws  = (float*)d_ws;

    k_front<<<PREP_BLOCKS + BDIM, 256, 0, stream>>>(mb, mm, mn, cx, cy,
                                                    emb, meb, mem_, men, ws, out);
    k_dis2<<<DIS_BLOCKS, 256, 0, stream>>>(fm, ws);
    k_combine<<<BDIM * NPARTS / 256, 256, 0, stream>>>(labels, ws);
    k_loss<<<1, 512, 0, stream>>>(ws, out);
}

// Round 10
// 45.208 us; speedup vs baseline: 6.7374x; 1.0441x over previous
//
#include <hip/hip_runtime.h>
#include <math.h>

#define NPARTS 64
#define CELL 28
#define CDIM 2048
#define BDIM 256
#define SPLIT 8
#define CH_PER_BLOCK (CDIM / SPLIT)     // 256 channels per slice
#define DIS_BLOCKS (BDIM * SPLIT)       // 2048 blocks for dis phase

// ---- d_ws layout (float offsets) ----
#define WS_SAME   0                                     // 16384
#define WS_PART   (WS_SAME + BDIM * NPARTS)             // 2048*192 = 393216
#define WS_MBT    (WS_PART + DIS_BLOCKS * 3 * NPARTS)   // f16 tables (negated)
#define WS_MMT    (WS_MBT + CDIM * NPARTS / 2)          // each = 65536 floats
#define WS_MNT    (WS_MMT + CDIM * NPARTS / 2)
#define WS_CELL   (WS_MNT + CDIM * NPARTS / 2)          // int cells, 16384
#define WS_DIMG   (WS_CELL + BDIM * NPARTS)             // 256*2 doubles (even offset)
#define WS_TICK   (WS_DIMG + 4 * BDIM)                  // 256 uint tickets

#define PREP_BLOCKS 1600   // 1600*256 = 3*CDIM*NPARTS + BDIM*NPARTS exactly

typedef _Float16 h2_t __attribute__((ext_vector_type(2)));

static __device__ __forceinline__ h2_t bperm_h2(int baddr, h2_t v) {
    int r = __builtin_amdgcn_ds_bpermute(baddr, __builtin_bit_cast(int, v));
    return __builtin_bit_cast(h2_t, r);
}

static __device__ __forceinline__ h2_t pack_h2(float a, float b) {
    return __builtin_bit_cast(h2_t, __builtin_amdgcn_cvt_pkrtz(a, b));
}

// ---------------------------------------------------------------------------
// Front kernel: blocks [0,1600) prep (negated-f16 transposed means + cells +
// ticket reset); blocks [1600,1856) distances_im + val (exact fp32 path).
// ---------------------------------------------------------------------------
__global__ __launch_bounds__(256) void k_front(
    const float* __restrict__ mb, const float* __restrict__ mm,
    const float* __restrict__ mn, const int* __restrict__ cx,
    const int* __restrict__ cy,
    const float* __restrict__ emb,
    const float* __restrict__ meb, const float* __restrict__ mem_,
    const float* __restrict__ men,
    float* __restrict__ ws, float* __restrict__ out)
{
    const int g = blockIdx.x;
    const int t = threadIdx.x;

    if (g < PREP_BLOCKS) {
        if (g == 0) ((unsigned*)ws)[WS_TICK + t] = 0u;   // reset 256 tickets
        const int tid = g * 256 + t;
        const int NM = CDIM * NPARTS;               // 131072 = 2^17
        if (tid < 3 * NM) {
            const int kind = tid >> 17;
            const int idx  = tid & (NM - 1);
            const int p = idx >> 11;
            const int c = idx & (CDIM - 1);
            const float* src = (kind == 0) ? mb : (kind == 1) ? mm : mn;
            _Float16* dst = (_Float16*)(ws + ((kind == 0) ? WS_MBT :
                                              (kind == 1) ? WS_MMT : WS_MNT));
            dst[((c >> 2) << 8) + (p << 2) + (c & 3)] = (_Float16)(-src[idx]);
        } else {
            const int t2 = tid - 3 * NM;            // < BDIM*NPARTS
            const int b = t2 & (BDIM - 1);
            const int p = t2 >> 8;
            const int x = cx[t2] / CELL;
            const int y = cy[t2] / CELL;
            ((int*)ws)[WS_CELL + b * NPARTS + p] = x * 8 + y;
        }
        return;
    }

    // ---- distances_im + val ----
    const int b = g - PREP_BLOCKS;
    const float* e = emb + (size_t)b * CDIM;

    float sb = 0.f, sm = 0.f, sn = 0.f;
    for (int c = t; c < CDIM; c += 256) {
        float v = e[c];
        float d0 = v - meb[c];  sb += d0 * d0;
        float d1 = v - mem_[c]; sm += d1 * d1;
        float d2 = v - men[c];  sn += d2 * d2;
    }
    for (int off = 32; off; off >>= 1) {
        sb += __shfl_down(sb, off);
        sm += __shfl_down(sm, off);
        sn += __shfl_down(sn, off);
    }
    __shared__ float red[3][4];
    const int wave = t >> 6;
    if ((t & 63) == 0) { red[0][wave] = sb; red[1][wave] = sm; red[2][wave] = sn; }
    __syncthreads();
    if (t == 0) {
        float tb = red[0][0] + red[0][1] + red[0][2] + red[0][3];
        float tm = red[1][0] + red[1][1] + red[1][2] + red[1][3];
        float tn = red[2][0] + red[2][1] + red[2][2] + red[2][3];
        float db = sqrtf(tb), dm = sqrtf(tm), dn = sqrtf(tn);
        out[b * 3 + 0] = db;
        out[b * 3 + 1] = dm;
        out[b * 3 + 2] = dn;
        int idx = 0; float best = db;
        if (dm < best) { best = dm; idx = 1; }
        if (dn < best) { idx = 2; }
        out[3 * BDIM + b] = (float)idx;
    }
}

// ---------------------------------------------------------------------------
// Dis kernel, f16-packed math + fused per-image combine.
// Block g: slice s = g>>8, image b = g&255  =>  g % 8 == b % 8, so all 8
// slice-blocks of an image land on ONE XCD (round-robin dispatch) and their
// partials are coherent in that XCD's L2 (mechanism validated in R7,
// absmax 0). The 8th arriver (ticket after vmcnt(0)) combines, writes
// same[] + per-image double sums with plain stores (kernel-end flush
// publishes them to k_loss).
// ---------------------------------------------------------------------------
__global__ __launch_bounds__(256) void k_dis2(
    const float* __restrict__ fm,
    const int* __restrict__ labels,
    float* __restrict__ ws)
{
    const int g = blockIdx.x;
    const int s = g >> 8, b = g & (BDIM - 1);
    const int t = threadIdx.x;
    const int lane = t & 63, w = t >> 6;

    const int cell  = ((const int*)ws)[WS_CELL + b * NPARTS + lane];
    const int baddr = cell << 2;           // byte address for bpermute

    const int c0 = s * CH_PER_BLOCK + w * 64;     // this wave's first channel
    const float* fmb = fm + (size_t)b * (CDIM * 64) + (size_t)c0 * 64;
    const uint2* mbt = (const uint2*)(ws + WS_MBT) + ((c0 >> 2) << 6) + lane;
    const uint2* mmt = (const uint2*)(ws + WS_MMT) + ((c0 >> 2) << 6) + lane;
    const uint2* mnt = (const uint2*)(ws + WS_MNT) + ((c0 >> 2) << 6) + lane;

    h2_t A00 = {0, 0}, A01 = {0, 0};   // mean b, pair slots (c0c1 / c2c3)
    h2_t A10 = {0, 0}, A11 = {0, 0};   // mean m
    h2_t A20 = {0, 0}, A21 = {0, 0};   // mean n

    #pragma unroll 4
    for (int k = 0; k < 16; ++k) {          // 4 channels per iter
        const float* r = fmb + k * 256;
        float v0 = r[lane];
        float v1 = r[64 + lane];
        float v2 = r[128 + lane];
        float v3 = r[192 + lane];
        uint2 nmb = mbt[k * 64];
        uint2 nmm = mmt[k * 64];
        uint2 nmn = mnt[k * 64];

        h2_t p01 = pack_h2(v0, v1);
        h2_t p23 = pack_h2(v2, v3);
        h2_t u01 = bperm_h2(baddr, p01);
        h2_t u23 = bperm_h2(baddr, p23);

        h2_t d;
        d = u01 + __builtin_bit_cast(h2_t, nmb.x); A00 += d * d;
        d = u23 + __builtin_bit_cast(h2_t, nmb.y); A01 += d * d;
        d = u01 + __builtin_bit_cast(h2_t, nmm.x); A10 += d * d;
        d = u23 + __builtin_bit_cast(h2_t, nmm.y); A11 += d * d;
        d = u01 + __builtin_bit_cast(h2_t, nmn.x); A20 += d * d;
        d = u23 + __builtin_bit_cast(h2_t, nmn.y); A21 += d * d;
    }

    float a0 = (float)A00.x + (float)A00.y + (float)A01.x + (float)A01.y;
    float a1 = (float)A10.x + (float)A10.y + (float)A11.x + (float)A11.y;
    float a2 = (float)A20.x + (float)A20.y + (float)A21.x + (float)A21.y;

    __shared__ float red[4][3][64];
    red[w][0][lane] = a0; red[w][1][lane] = a1; red[w][2][lane] = a2;
    __syncthreads();
    if (t < 64) {
        float s0 = red[0][0][t] + red[1][0][t] + red[2][0][t] + red[3][0][t];
        float s1 = red[0][1][t] + red[1][1][t] + red[2][1][t] + red[3][1][t];
        float s2 = red[0][2][t] + red[1][2][t] + red[2][2][t] + red[3][2][t];
        float* po = ws + WS_PART + (size_t)(b * SPLIT + s) * 192;
        po[t] = s0; po[64 + t] = s1; po[128 + t] = s2;
    }

    // ---- per-image ticket (no fence; partials stay in this XCD's L2) ----
    asm volatile("s_waitcnt vmcnt(0)" ::: "memory");
    __shared__ unsigned flag;
    if (t == 0) flag = atomicAdd(&((unsigned*)ws)[WS_TICK + b], 1u);
    __syncthreads();
    if (flag != SPLIT - 1) return;

    // ---- image epilogue (8th arriver; same XCD as all 8 writers) ----
    __shared__ float sm2[3][64];
    const float* pp = ws + WS_PART + (size_t)(b * SPLIT) * 192;
    if (t < 192) {
        const int j = t >> 6, p = t & 63;
        float acc = 0.f;
        #pragma unroll
        for (int sl = 0; sl < SPLIT; ++sl)
            acc += __hip_atomic_load(pp + sl * 192 + j * 64 + p,
                                     __ATOMIC_RELAXED, __HIP_MEMORY_SCOPE_AGENT);
        sm2[j][p] = acc;
    }
    __syncthreads();

    if (t < 64) {
        float db = sqrtf(sm2[0][t]);
        float dm = sqrtf(sm2[1][t]);
        float dn = sqrtf(sm2[2][t]);
        const int lab = labels[b];
        float same_v = (lab == 0) ? db : ((lab == 1) ? dm : dn);
        ws[WS_SAME + b * NPARTS + t] = same_v;      // plain store: kernel-end flush
        double ds = (double)same_v;
        double d3 = (double)(db + dm + dn);
        for (int off = 32; off; off >>= 1) {
            ds += __shfl_down(ds, off);
            d3 += __shfl_down(d3, off);
        }
        if (t == 0) {
            double* dimg = (double*)(ws + WS_DIMG);
            dimg[2 * b]     = ds;
            dimg[2 * b + 1] = d3;
        }
    }
}

// ---------------------------------------------------------------------------
// Deterministic final loss (single block, 512 threads): reads 256 per-image
// double pairs + 16384 same floats.
// ---------------------------------------------------------------------------
__global__ __launch_bounds__(512) void k_loss(
    const float* __restrict__ ws, float* __restrict__ out)
{
    const int t = threadIdx.x;
    const int N = BDIM * NPARTS;
    const float* same = ws + WS_SAME;
    const double* dimg = (const double*)(ws + WS_DIMG);

    double ss = 0.0, s3 = 0.0;
    if (t < BDIM) { ss = dimg[2 * t]; s3 = dimg[2 * t + 1]; }

    __shared__ double r1[512], r2[512];
    r1[t] = s3; r2[t] = ss;
    __syncthreads();
    for (int off = 256; off; off >>= 1) {
        if (t < off) { r1[t] += r1[t + off]; r2[t] += r2[t + off]; }
        __syncthreads();
    }
    __shared__ float dmS;
    if (t == 0) dmS = (float)((r1[0] - r2[0]) / (double)(BDIM * 2 * NPARTS));
    __syncthreads();
    const float dmean = dmS;

    double sl = 0.0;
    for (int i = t; i < N; i += 512) {
        float v = 1.0f + same[i] - dmean;
        sl += (v > 0.f) ? (double)v : 0.0;
    }
    r1[t] = sl;
    __syncthreads();
    for (int off = 256; off; off >>= 1) {
        if (t < off) r1[t] += r1[t + off];
        __syncthreads();
    }
    if (t == 0) out[3 * BDIM + BDIM] = (float)(r1[0] / (double)N);
}

extern "C" void kernel_launch(void* const* d_in, const int* in_sizes, int n_in,
                              void* d_out, int out_size, void* d_ws, size_t ws_size,
                              hipStream_t stream)
{
    const int*   labels = (const int*)  d_in[0];
    const float* emb    = (const float*)d_in[1];
    const float* fm     = (const float*)d_in[2];
    const float* mb     = (const float*)d_in[3];
    const float* mm     = (const float*)d_in[4];
    const float* mn     = (const float*)d_in[5];
    const int*   cx     = (const int*)  d_in[6];
    const int*   cy     = (const int*)  d_in[7];
    const float* meb    = (const float*)d_in[8];
    const float* mem_   = (const float*)d_in[9];
    const float* men    = (const float*)d_in[10];

    float* out = (float*)d_out;
    float* ws  = (float*)d_ws;

    k_front<<<PREP_BLOCKS + BDIM, 256, 0, stream>>>(mb, mm, mn, cx, cy,
                                                    emb, meb, mem_, men, ws, out);
    k_dis2<<<DIS_BLOCKS, 256, 0, stream>>>(fm, labels, ws);
    k_loss<<<1, 512, 0, stream>>>(ws, out);
}

// Round 11
// 45.067 us; speedup vs baseline: 6.7586x; 1.0031x over previous
//
#include <hip/hip_runtime.h>
#include <math.h>

#define NPARTS 64
#define CELL 28
#define CDIM 2048
#define BDIM 256
#define SPLIT 8
#define CH_PER_BLOCK (CDIM / SPLIT)     // 256 channels per slice
#define DIS_BLOCKS (BDIM * SPLIT)       // 2048 blocks for dis phase

// ---- d_ws layout (float offsets) ----
#define WS_SAME   0                                     // 16384
#define WS_PART   (WS_SAME + BDIM * NPARTS)             // 2048*192 = 393216
#define WS_MBT    (WS_PART + DIS_BLOCKS * 3 * NPARTS)   // f16 tables (negated)
#define WS_MMT    (WS_MBT + CDIM * NPARTS / 2)          // each = 65536 floats
#define WS_MNT    (WS_MMT + CDIM * NPARTS / 2)
#define WS_CELL   (WS_MNT + CDIM * NPARTS / 2)          // int cells, 16384
#define WS_DIMG   (WS_CELL + BDIM * NPARTS)             // 256*2 doubles (even offset)
#define WS_TICK   (WS_DIMG + 4 * BDIM)                  // 256 uint tickets

// k_front geometry: 384 transpose blocks (3 kinds x 512 quads x 64 parts)
// + 64 cell blocks + 256 distance blocks
#define TR_BLOCKS   384
#define PREP_BLOCKS (TR_BLOCKS + 64)    // 448

typedef _Float16 h2_t __attribute__((ext_vector_type(2)));

static __device__ __forceinline__ h2_t bperm_h2(int baddr, h2_t v) {
    int r = __builtin_amdgcn_ds_bpermute(baddr, __builtin_bit_cast(int, v));
    return __builtin_bit_cast(h2_t, r);
}

static __device__ __forceinline__ h2_t pack_h2(float a, float b) {
    return __builtin_bit_cast(h2_t, __builtin_amdgcn_cvt_pkrtz(a, b));
}

// ---------------------------------------------------------------------------
// Front kernel.
// Blocks [0,384): mean transpose, lane = part: thread (kind, cq, p) reads
//   float4 m[p][4cq..4cq+3], writes uint2 of negated f16 at halves
//   cq*256 + p*4 -- consecutive lanes (p) -> consecutive 8 B chunks,
//   fully coalesced 512 B per wave-store (vs 16-line scatter before).
// Blocks [384,448): cell precompute. Blocks [448,704): distances_im + val.
// ---------------------------------------------------------------------------
__global__ __launch_bounds__(256) void k_front(
    const float* __restrict__ mb, const float* __restrict__ mm,
    const float* __restrict__ mn, const int* __restrict__ cx,
    const int* __restrict__ cy,
    const float* __restrict__ emb,
    const float* __restrict__ meb, const float* __restrict__ mem_,
    const float* __restrict__ men,
    float* __restrict__ ws, float* __restrict__ out)
{
    const int g = blockIdx.x;
    const int t = threadIdx.x;

    if (g < TR_BLOCKS) {
        if (g == 0) ((unsigned*)ws)[WS_TICK + t] = 0u;   // reset 256 tickets
        const int tid  = g * 256 + t;        // 0..98303
        const int kind = tid >> 15;          // 32768 threads per kind
        const int idx  = tid & 32767;
        const int cq   = idx >> 6;           // channel quad 0..511
        const int p    = idx & 63;           // part = lane
        const float* src = (kind == 0) ? mb : (kind == 1) ? mm : mn;
        const float4 s4 = *(const float4*)(src + (size_t)p * CDIM + cq * 4);
        uint2 v;
        v.x = __builtin_bit_cast(unsigned, pack_h2(-s4.x, -s4.y));
        v.y = __builtin_bit_cast(unsigned, pack_h2(-s4.z, -s4.w));
        _Float16* dst = (_Float16*)(ws + ((kind == 0) ? WS_MBT :
                                          (kind == 1) ? WS_MMT : WS_MNT));
        *(uint2*)(dst + ((cq << 8) + (p << 2))) = v;
        return;
    }

    if (g < PREP_BLOCKS) {
        const int t2 = (g - TR_BLOCKS) * 256 + t;   // < BDIM*NPARTS, = p*256+b
        const int b = t2 & (BDIM - 1);
        const int p = t2 >> 8;
        const int x = cx[t2] / CELL;
        const int y = cy[t2] / CELL;
        ((int*)ws)[WS_CELL + b * NPARTS + p] = x * 8 + y;
        return;
    }

    // ---- distances_im + val (exact fp32 path) ----
    const int b = g - PREP_BLOCKS;
    const float* e = emb + (size_t)b * CDIM;

    float sb = 0.f, sm = 0.f, sn = 0.f;
    for (int c = t; c < CDIM; c += 256) {
        float v = e[c];
        float d0 = v - meb[c];  sb += d0 * d0;
        float d1 = v - mem_[c]; sm += d1 * d1;
        float d2 = v - men[c];  sn += d2 * d2;
    }
    for (int off = 32; off; off >>= 1) {
        sb += __shfl_down(sb, off);
        sm += __shfl_down(sm, off);
        sn += __shfl_down(sn, off);
    }
    __shared__ float red[3][4];
    const int wave = t >> 6;
    if ((t & 63) == 0) { red[0][wave] = sb; red[1][wave] = sm; red[2][wave] = sn; }
    __syncthreads();
    if (t == 0) {
        float tb = red[0][0] + red[0][1] + red[0][2] + red[0][3];
        float tm = red[1][0] + red[1][1] + red[1][2] + red[1][3];
        float tn = red[2][0] + red[2][1] + red[2][2] + red[2][3];
        float db = sqrtf(tb), dm = sqrtf(tm), dn = sqrtf(tn);
        out[b * 3 + 0] = db;
        out[b * 3 + 1] = dm;
        out[b * 3 + 2] = dn;
        int idx = 0; float best = db;
        if (dm < best) { best = dm; idx = 1; }
        if (dn < best) { idx = 2; }
        out[3 * BDIM + b] = (float)idx;
    }
}

// ---------------------------------------------------------------------------
// Dis kernel, f16-packed math + fused per-image combine (same-XCD ticket).
// Block g: slice s = g>>8, image b = g&255 => g % 8 == b % 8: all 8 slice
// blocks of an image land on ONE XCD, partials coherent in that L2.
// ---------------------------------------------------------------------------
__global__ __launch_bounds__(256) void k_dis2(
    const float* __restrict__ fm,
    const int* __restrict__ labels,
    float* __restrict__ ws)
{
    const int g = blockIdx.x;
    const int s = g >> 8, b = g & (BDIM - 1);
    const int t = threadIdx.x;
    const int lane = t & 63, w = t >> 6;

    const int cell  = ((const int*)ws)[WS_CELL + b * NPARTS + lane];
    const int baddr = cell << 2;           // byte address for bpermute

    const int c0 = s * CH_PER_BLOCK + w * 64;     // this wave's first channel
    const float* fmb = fm + (size_t)b * (CDIM * 64) + (size_t)c0 * 64;
    const uint2* mbt = (const uint2*)(ws + WS_MBT) + ((c0 >> 2) << 6) + lane;
    const uint2* mmt = (const uint2*)(ws + WS_MMT) + ((c0 >> 2) << 6) + lane;
    const uint2* mnt = (const uint2*)(ws + WS_MNT) + ((c0 >> 2) << 6) + lane;

    h2_t A00 = {0, 0}, A01 = {0, 0};   // mean b, pair slots (c0c1 / c2c3)
    h2_t A10 = {0, 0}, A11 = {0, 0};   // mean m
    h2_t A20 = {0, 0}, A21 = {0, 0};   // mean n

    #pragma unroll 4
    for (int k = 0; k < 16; ++k) {          // 4 channels per iter
        const float* r = fmb + k * 256;
        float v0 = r[lane];
        float v1 = r[64 + lane];
        float v2 = r[128 + lane];
        float v3 = r[192 + lane];
        uint2 nmb = mbt[k * 64];
        uint2 nmm = mmt[k * 64];
        uint2 nmn = mnt[k * 64];

        h2_t p01 = pack_h2(v0, v1);
        h2_t p23 = pack_h2(v2, v3);
        h2_t u01 = bperm_h2(baddr, p01);
        h2_t u23 = bperm_h2(baddr, p23);

        h2_t d;
        d = u01 + __builtin_bit_cast(h2_t, nmb.x); A00 += d * d;
        d = u23 + __builtin_bit_cast(h2_t, nmb.y); A01 += d * d;
        d = u01 + __builtin_bit_cast(h2_t, nmm.x); A10 += d * d;
        d = u23 + __builtin_bit_cast(h2_t, nmm.y); A11 += d * d;
        d = u01 + __builtin_bit_cast(h2_t, nmn.x); A20 += d * d;
        d = u23 + __builtin_bit_cast(h2_t, nmn.y); A21 += d * d;
    }

    float a0 = (float)A00.x + (float)A00.y + (float)A01.x + (float)A01.y;
    float a1 = (float)A10.x + (float)A10.y + (float)A11.x + (float)A11.y;
    float a2 = (float)A20.x + (float)A20.y + (float)A21.x + (float)A21.y;

    __shared__ float red[4][3][64];
    red[w][0][lane] = a0; red[w][1][lane] = a1; red[w][2][lane] = a2;
    __syncthreads();
    if (t < 64) {
        float s0 = red[0][0][t] + red[1][0][t] + red[2][0][t] + red[3][0][t];
        float s1 = red[0][1][t] + red[1][1][t] + red[2][1][t] + red[3][1][t];
        float s2 = red[0][2][t] + red[1][2][t] + red[2][2][t] + red[3][2][t];
        float* po = ws + WS_PART + (size_t)(b * SPLIT + s) * 192;
        po[t] = s0; po[64 + t] = s1; po[128 + t] = s2;
    }

    // ---- per-image ticket (no fence; partials stay in this XCD's L2) ----
    asm volatile("s_waitcnt vmcnt(0)" ::: "memory");
    __shared__ unsigned flag;
    if (t == 0) flag = atomicAdd(&((unsigned*)ws)[WS_TICK + b], 1u);
    __syncthreads();
    if (flag != SPLIT - 1) return;

    // ---- image epilogue (8th arriver; same XCD as all 8 writers) ----
    __shared__ float sm2[3][64];
    const float* pp = ws + WS_PART + (size_t)(b * SPLIT) * 192;
    if (t < 192) {
        const int j = t >> 6, p = t & 63;
        float acc = 0.f;
        #pragma unroll
        for (int sl = 0; sl < SPLIT; ++sl)
            acc += __hip_atomic_load(pp + sl * 192 + j * 64 + p,
                                     __ATOMIC_RELAXED, __HIP_MEMORY_SCOPE_AGENT);
        sm2[j][p] = acc;
    }
    __syncthreads();

    if (t < 64) {
        float db = sqrtf(sm2[0][t]);
        float dm = sqrtf(sm2[1][t]);
        float dn = sqrtf(sm2[2][t]);
        const int lab = labels[b];
        float same_v = (lab == 0) ? db : ((lab == 1) ? dm : dn);
        ws[WS_SAME + b * NPARTS + t] = same_v;      // plain store: kernel-end flush
        double ds = (double)same_v;
        double d3 = (double)(db + dm + dn);
        for (int off = 32; off; off >>= 1) {
            ds += __shfl_down(ds, off);
            d3 += __shfl_down(d3, off);
        }
        if (t == 0) {
            double* dimg = (double*)(ws + WS_DIMG);
            dimg[2 * b]     = ds;
            dimg[2 * b + 1] = d3;
        }
    }
}

// ---------------------------------------------------------------------------
// Deterministic final loss (single block, 512 threads)
// ---------------------------------------------------------------------------
__global__ __launch_bounds__(512) void k_loss(
    const float* __restrict__ ws, float* __restrict__ out)
{
    const int t = threadIdx.x;
    const int N = BDIM * NPARTS;
    const float* same = ws + WS_SAME;
    const double* dimg = (const double*)(ws + WS_DIMG);

    double ss = 0.0, s3 = 0.0;
    if (t < BDIM) { ss = dimg[2 * t]; s3 = dimg[2 * t + 1]; }

    __shared__ double r1[512], r2[512];
    r1[t] = s3; r2[t] = ss;
    __syncthreads();
    for (int off = 256; off; off >>= 1) {
        if (t < off) { r1[t] += r1[t + off]; r2[t] += r2[t + off]; }
        __syncthreads();
    }
    __shared__ float dmS;
    if (t == 0) dmS = (float)((r1[0] - r2[0]) / (double)(BDIM * 2 * NPARTS));
    __syncthreads();
    const float dmean = dmS;

    double sl = 0.0;
    for (int i = t; i < N; i += 512) {
        float v = 1.0f + same[i] - dmean;
        sl += (v > 0.f) ? (double)v : 0.0;
    }
    r1[t] = sl;
    __syncthreads();
    for (int off = 256; off; off >>= 1) {
        if (t < off) r1[t] += r1[t + off];
        __syncthreads();
    }
    if (t == 0) out[3 * BDIM + BDIM] = (float)(r1[0] / (double)N);
}

extern "C" void kernel_launch(void* const* d_in, const int* in_sizes, int n_in,
                              void* d_out, int out_size, void* d_ws, size_t ws_size,
                              hipStream_t stream)
{
    const int*   labels = (const int*)  d_in[0];
    const float* emb    = (const float*)d_in[1];
    const float* fm     = (const float*)d_in[2];
    const float* mb     = (const float*)d_in[3];
    const float* mm     = (const float*)d_in[4];
    const float* mn     = (const float*)d_in[5];
    const int*   cx     = (const int*)  d_in[6];
    const int*   cy     = (const int*)  d_in[7];
    const float* meb    = (const float*)d_in[8];
    const float* mem_   = (const float*)d_in[9];
    const float* men    = (const float*)d_in[10];

    float* out = (float*)d_out;
    float* ws  = (float*)d_ws;

    k_front<<<PREP_BLOCKS + BDIM, 256, 0, stream>>>(mb, mm, mn, cx, cy,
                                                    emb, meb, mem_, men, ws, out);
    k_dis2<<<DIS_BLOCKS, 256, 0, stream>>>(fm, labels, ws);
    k_loss<<<1, 512, 0, stream>>>(ws, out);
}

// Round 12
// 41.819 us; speedup vs baseline: 7.2834x; 1.0777x over previous
//
#include <hip/hip_runtime.h>
#include <math.h>

#define NPARTS 64
#define CELL 28
#define CDIM 2048
#define BDIM 256
#define SPLIT 8
#define CH_PER_BLOCK (CDIM / SPLIT)     // 256 channels per slice
#define DIS_BLOCKS (BDIM * SPLIT)       // 2048 blocks for dis phase

// ---- d_ws layout (float offsets) ----
#define WS_SAME   0                                     // 16384
#define WS_PART   (WS_SAME + BDIM * NPARTS)             // 2048*192 = 393216
#define WS_MBT    (WS_PART + DIS_BLOCKS * 3 * NPARTS)   // f16 tables (negated)
#define WS_MMT    (WS_MBT + CDIM * NPARTS / 2)          // each = 65536 floats
#define WS_MNT    (WS_MMT + CDIM * NPARTS / 2)
#define WS_CELL   (WS_MNT + CDIM * NPARTS / 2)          // int cells, 16384
#define WS_DIMG   (WS_CELL + BDIM * NPARTS)             // 256*2 doubles (even offset)
#define WS_TICK   (WS_DIMG + 4 * BDIM)                  // 256 uint tickets

// k_prep geometry: 384 transpose blocks + 64 cell blocks
#define TR_BLOCKS   384
#define PREP_BLOCKS (TR_BLOCKS + 64)    // 448

typedef _Float16 h2_t __attribute__((ext_vector_type(2)));

static __device__ __forceinline__ h2_t bperm_h2(int baddr, h2_t v) {
    int r = __builtin_amdgcn_ds_bpermute(baddr, __builtin_bit_cast(int, v));
    return __builtin_bit_cast(h2_t, r);
}

static __device__ __forceinline__ h2_t pack_h2(float a, float b) {
    return __builtin_bit_cast(h2_t, __builtin_amdgcn_cvt_pkrtz(a, b));
}

// ---------------------------------------------------------------------------
// Prep kernel (pure; unblocks k_dis2 fast).
// Blocks [0,384): mean transpose, lane = part (coalesced uint2 writes).
// Blocks [384,448): cell precompute. Block 0 also resets tickets.
// ---------------------------------------------------------------------------
__global__ __launch_bounds__(256) void k_prep(
    const float* __restrict__ mb, const float* __restrict__ mm,
    const float* __restrict__ mn, const int* __restrict__ cx,
    const int* __restrict__ cy, float* __restrict__ ws)
{
    const int g = blockIdx.x;
    const int t = threadIdx.x;

    if (g < TR_BLOCKS) {
        if (g == 0) ((unsigned*)ws)[WS_TICK + t] = 0u;   // reset 256 tickets
        const int tid  = g * 256 + t;        // 0..98303
        const int kind = tid >> 15;          // 32768 threads per kind
        const int idx  = tid & 32767;
        const int cq   = idx >> 6;           // channel quad 0..511
        const int p    = idx & 63;           // part = lane
        const float* src = (kind == 0) ? mb : (kind == 1) ? mm : mn;
        const float4 s4 = *(const float4*)(src + (size_t)p * CDIM + cq * 4);
        uint2 v;
        v.x = __builtin_bit_cast(unsigned, pack_h2(-s4.x, -s4.y));
        v.y = __builtin_bit_cast(unsigned, pack_h2(-s4.z, -s4.w));
        _Float16* dst = (_Float16*)(ws + ((kind == 0) ? WS_MBT :
                                          (kind == 1) ? WS_MMT : WS_MNT));
        *(uint2*)(dst + ((cq << 8) + (p << 2))) = v;
        return;
    }

    const int t2 = (g - TR_BLOCKS) * 256 + t;   // < BDIM*NPARTS, = p*256+b
    const int b = t2 & (BDIM - 1);
    const int p = t2 >> 8;
    const int x = cx[t2] / CELL;
    const int y = cy[t2] / CELL;
    ((int*)ws)[WS_CELL + b * NPARTS + p] = x * 8 + y;
}

// ---------------------------------------------------------------------------
// Dis kernel, f16-packed math + fused per-image combine (same-XCD ticket).
// Block g: slice s = g>>8, image b = g&255 => g % 8 == b % 8: all 8 slice
// blocks of an image land on ONE XCD, partials coherent in that L2.
// (unchanged from R10/R11 - validated, absmax 0)
// ---------------------------------------------------------------------------
__global__ __launch_bounds__(256) void k_dis2(
    const float* __restrict__ fm,
    const int* __restrict__ labels,
    float* __restrict__ ws)
{
    const int g = blockIdx.x;
    const int s = g >> 8, b = g & (BDIM - 1);
    const int t = threadIdx.x;
    const int lane = t & 63, w = t >> 6;

    const int cell  = ((const int*)ws)[WS_CELL + b * NPARTS + lane];
    const int baddr = cell << 2;           // byte address for bpermute

    const int c0 = s * CH_PER_BLOCK + w * 64;     // this wave's first channel
    const float* fmb = fm + (size_t)b * (CDIM * 64) + (size_t)c0 * 64;
    const uint2* mbt = (const uint2*)(ws + WS_MBT) + ((c0 >> 2) << 6) + lane;
    const uint2* mmt = (const uint2*)(ws + WS_MMT) + ((c0 >> 2) << 6) + lane;
    const uint2* mnt = (const uint2*)(ws + WS_MNT) + ((c0 >> 2) << 6) + lane;

    h2_t A00 = {0, 0}, A01 = {0, 0};   // mean b, pair slots (c0c1 / c2c3)
    h2_t A10 = {0, 0}, A11 = {0, 0};   // mean m
    h2_t A20 = {0, 0}, A21 = {0, 0};   // mean n

    #pragma unroll 4
    for (int k = 0; k < 16; ++k) {          // 4 channels per iter
        const float* r = fmb + k * 256;
        float v0 = r[lane];
        float v1 = r[64 + lane];
        float v2 = r[128 + lane];
        float v3 = r[192 + lane];
        uint2 nmb = mbt[k * 64];
        uint2 nmm = mmt[k * 64];
        uint2 nmn = mnt[k * 64];

        h2_t p01 = pack_h2(v0, v1);
        h2_t p23 = pack_h2(v2, v3);
        h2_t u01 = bperm_h2(baddr, p01);
        h2_t u23 = bperm_h2(baddr, p23);

        h2_t d;
        d = u01 + __builtin_bit_cast(h2_t, nmb.x); A00 += d * d;
        d = u23 + __builtin_bit_cast(h2_t, nmb.y); A01 += d * d;
        d = u01 + __builtin_bit_cast(h2_t, nmm.x); A10 += d * d;
        d = u23 + __builtin_bit_cast(h2_t, nmm.y); A11 += d * d;
        d = u01 + __builtin_bit_cast(h2_t, nmn.x); A20 += d * d;
        d = u23 + __builtin_bit_cast(h2_t, nmn.y); A21 += d * d;
    }

    float a0 = (float)A00.x + (float)A00.y + (float)A01.x + (float)A01.y;
    float a1 = (float)A10.x + (float)A10.y + (float)A11.x + (float)A11.y;
    float a2 = (float)A20.x + (float)A20.y + (float)A21.x + (float)A21.y;

    __shared__ float red[4][3][64];
    red[w][0][lane] = a0; red[w][1][lane] = a1; red[w][2][lane] = a2;
    __syncthreads();
    if (t < 64) {
        float s0 = red[0][0][t] + red[1][0][t] + red[2][0][t] + red[3][0][t];
        float s1 = red[0][1][t] + red[1][1][t] + red[2][1][t] + red[3][1][t];
        float s2 = red[0][2][t] + red[1][2][t] + red[2][2][t] + red[3][2][t];
        float* po = ws + WS_PART + (size_t)(b * SPLIT + s) * 192;
        po[t] = s0; po[64 + t] = s1; po[128 + t] = s2;
    }

    // ---- per-image ticket (no fence; partials stay in this XCD's L2) ----
    asm volatile("s_waitcnt vmcnt(0)" ::: "memory");
    __shared__ unsigned flag;
    if (t == 0) flag = atomicAdd(&((unsigned*)ws)[WS_TICK + b], 1u);
    __syncthreads();
    if (flag != SPLIT - 1) return;

    // ---- image epilogue (8th arriver; same XCD as all 8 writers) ----
    __shared__ float sm2[3][64];
    const float* pp = ws + WS_PART + (size_t)(b * SPLIT) * 192;
    if (t < 192) {
        const int j = t >> 6, p = t & 63;
        float acc = 0.f;
        #pragma unroll
        for (int sl = 0; sl < SPLIT; ++sl)
            acc += __hip_atomic_load(pp + sl * 192 + j * 64 + p,
                                     __ATOMIC_RELAXED, __HIP_MEMORY_SCOPE_AGENT);
        sm2[j][p] = acc;
    }
    __syncthreads();

    if (t < 64) {
        float db = sqrtf(sm2[0][t]);
        float dm = sqrtf(sm2[1][t]);
        float dn = sqrtf(sm2[2][t]);
        const int lab = labels[b];
        float same_v = (lab == 0) ? db : ((lab == 1) ? dm : dn);
        ws[WS_SAME + b * NPARTS + t] = same_v;      // plain store: kernel-end flush
        double ds = (double)same_v;
        double d3 = (double)(db + dm + dn);
        for (int off = 32; off; off >>= 1) {
            ds += __shfl_down(ds, off);
            d3 += __shfl_down(d3, off);
        }
        if (t == 0) {
            double* dimg = (double*)(ws + WS_DIMG);
            dimg[2 * b]     = ds;
            dimg[2 * b + 1] = d3;
        }
    }
}

// ---------------------------------------------------------------------------
// Tail kernel: block 0 = deterministic loss; blocks 1..256 = distances_im +
// val for image g-1 (independent of k_dis2, hidden under the loss block).
// ---------------------------------------------------------------------------
__global__ __launch_bounds__(256) void k_tail(
    const float* __restrict__ emb,
    const float* __restrict__ meb, const float* __restrict__ mem_,
    const float* __restrict__ men,
    const float* __restrict__ ws, float* __restrict__ out)
{
    const int g = blockIdx.x;
    const int t = threadIdx.x;

    if (g == 0) {
        // ---- final loss (reads k_dis2's same[] + dimg, stream-ordered) ----
        const int N = BDIM * NPARTS;
        const float* same = ws + WS_SAME;
        const double* dimg = (const double*)(ws + WS_DIMG);

        double ss = dimg[2 * t];        // t spans 0..255 = all images
        double s3 = dimg[2 * t + 1];

        __shared__ double r1[256], r2[256];
        r1[t] = s3; r2[t] = ss;
        __syncthreads();
        for (int off = 128; off; off >>= 1) {
            if (t < off) { r1[t] += r1[t + off]; r2[t] += r2[t + off]; }
            __syncthreads();
        }
        __shared__ float dmS;
        if (t == 0) dmS = (float)((r1[0] - r2[0]) / (double)(BDIM * 2 * NPARTS));
        __syncthreads();
        const float dmean = dmS;

        double sl = 0.0;
        #pragma unroll 4
        for (int i = t; i < N; i += 256) {
            float v = 1.0f + same[i] - dmean;
            sl += (v > 0.f) ? (double)v : 0.0;
        }
        r1[t] = sl;
        __syncthreads();
        for (int off = 128; off; off >>= 1) {
            if (t < off) r1[t] += r1[t + off];
            __syncthreads();
        }
        if (t == 0) out[3 * BDIM + BDIM] = (float)(r1[0] / (double)N);
        return;
    }

    // ---- distances_im + val (exact fp32 path), image b = g-1 ----
    const int b = g - 1;
    const float* e = emb + (size_t)b * CDIM;

    float sb = 0.f, sm = 0.f, sn = 0.f;
    for (int c = t; c < CDIM; c += 256) {
        float v = e[c];
        float d0 = v - meb[c];  sb += d0 * d0;
        float d1 = v - mem_[c]; sm += d1 * d1;
        float d2 = v - men[c];  sn += d2 * d2;
    }
    for (int off = 32; off; off >>= 1) {
        sb += __shfl_down(sb, off);
        sm += __shfl_down(sm, off);
        sn += __shfl_down(sn, off);
    }
    __shared__ float red[3][4];
    const int wave = t >> 6;
    if ((t & 63) == 0) { red[0][wave] = sb; red[1][wave] = sm; red[2][wave] = sn; }
    __syncthreads();
    if (t == 0) {
        float tb = red[0][0] + red[0][1] + red[0][2] + red[0][3];
        float tm = red[1][0] + red[1][1] + red[1][2] + red[1][3];
        float tn = red[2][0] + red[2][1] + red[2][2] + red[2][3];
        float db = sqrtf(tb), dm = sqrtf(tm), dn = sqrtf(tn);
        out[b * 3 + 0] = db;
        out[b * 3 + 1] = dm;
        out[b * 3 + 2] = dn;
        int idx = 0; float best = db;
        if (dm < best) { best = dm; idx = 1; }
        if (dn < best) { idx = 2; }
        out[3 * BDIM + b] = (float)idx;
    }
}

extern "C" void kernel_launch(void* const* d_in, const int* in_sizes, int n_in,
                              void* d_out, int out_size, void* d_ws, size_t ws_size,
                              hipStream_t stream)
{
    const int*   labels = (const int*)  d_in[0];
    const float* emb    = (const float*)d_in[1];
    const float* fm     = (const float*)d_in[2];
    const float* mb     = (const float*)d_in[3];
    const float* mm     = (const float*)d_in[4];
    const float* mn     = (const float*)d_in[5];
    const int*   cx     = (const int*)  d_in[6];
    const int*   cy     = (const int*)  d_in[7];
    const float* meb    = (const float*)d_in[8];
    const float* mem_   = (const float*)d_in[9];
    const float* men    = (const float*)d_in[10];

    float* out = (float*)d_out;
    float* ws  = (float*)d_ws;

    k_prep<<<PREP_BLOCKS, 256, 0, stream>>>(mb, mm, mn, cx, cy, ws);
    k_dis2<<<DIS_BLOCKS, 256, 0, stream>>>(fm, labels, ws);
    k_tail<<<1 + BDIM, 256, 0, stream>>>(emb, meb, mem_, men, ws, out);
}